// Round 12
// baseline (101.024 us; speedup 1.0000x reference)
//
#include <hip/hip_runtime.h>
#include <math.h>

#define H   128
#define NS  1024
#define NE  512
#define M   1024
#define K2  2.8853900817779268f   // 2*log2(e): tanh(x) = 1 - 2/(1+exp2(K2*x))

__device__ __forceinline__ float exp2_fast(float x) {
#if __has_builtin(__builtin_amdgcn_exp2f)
    return __builtin_amdgcn_exp2f(x);
#else
    return __expf(x * 0.6931471805599453f);
#endif
}

__device__ __forceinline__ float fast_tanh(float x) {
    float e = __expf(2.0f * x);
    float r = __builtin_amdgcn_rcpf(1.0f + e);
    return 1.0f - 2.0f * r;
}

// ---- transpose (+K2 scale) the weight matrices ---------------------------
__global__ __launch_bounds__(256) void k_tr(const float* __restrict__ Wc_s,
                                            const float* __restrict__ Wc_e,
                                            const float* __restrict__ W_lin,
                                            float* __restrict__ WT_s1, float* __restrict__ WT_s2,
                                            float* __restrict__ WT_e1, float* __restrict__ WT_e2,
                                            float* __restrict__ WT_lin) {
    int idx = blockIdx.x * 256 + threadIdx.x;
    if (idx < 65536) {
        int t = idx >> 14, r = idx & 16383, k = r >> 7, hh = r & 127;
        const float* src = (t < 2) ? Wc_s : Wc_e;
        int off = (t & 1) * H;
        float v = K2 * src[hh * 256 + off + k];
        float* dst = (t == 0) ? WT_s1 : (t == 1) ? WT_s2 : (t == 2) ? WT_e1 : WT_e2;
        dst[r] = v;
    } else {
        int j2 = idx - 65536;             // [0, 49152)
        int k = j2 >> 7, a = j2 & 127;
        WT_lin[j2] = W_lin[a * 384 + k];
    }
}

// ---- projections -> exp2 domain: E = exp2(K2*(XW^T + b)) -----------------
__global__ __launch_bounds__(256) void k_proj(const float* __restrict__ stmts,
                                              const float* __restrict__ eres,
                                              const float* __restrict__ attender,
                                              const float* __restrict__ WT_s1,
                                              const float* __restrict__ WT_s2,
                                              const float* __restrict__ WT_e1,
                                              const float* __restrict__ WT_e2,
                                              const float* __restrict__ bc_s,
                                              const float* __restrict__ bc_e,
                                              float* __restrict__ EA_s, float* __restrict__ EB_s,
                                              float* __restrict__ EA_e, float* __restrict__ EB_e) {
    int b = blockIdx.x;
    const float *X, *WT, *bias; float* O; int r0;
    if (b < 256)      { X = stmts;    WT = WT_s1; bias = bc_s;    O = EA_s; r0 = b * 4; }
    else if (b < 512) { X = attender; WT = WT_s2; bias = nullptr; O = EB_s; r0 = (b - 256) * 4; }
    else if (b < 640) { X = eres;     WT = WT_e1; bias = bc_e;    O = EA_e; r0 = (b - 512) * 4; }
    else              { X = attender; WT = WT_e2; bias = nullptr; O = EB_e; r0 = (b - 640) * 4; }
    __shared__ float xr[4][H];
    __shared__ float red[4][H];
    int tid  = threadIdx.x;
    int t    = tid & 127;
    int half = tid >> 7;
    float* xf = &xr[0][0];
    xf[tid]       = X[r0 * H + tid];
    xf[tid + 256] = X[r0 * H + 256 + tid];
    __syncthreads();
    float b0 = (bias && half == 0) ? K2 * bias[t] : 0.0f;
    float acc[4] = {b0, b0, b0, b0};
    int k0 = half * 64;
    #pragma unroll 8
    for (int k = k0; k < k0 + 64; ++k) {
        float wv = WT[k * H + t];
        #pragma unroll
        for (int r = 0; r < 4; ++r) acc[r] += xr[r][k] * wv;
    }
    if (half) {
        #pragma unroll
        for (int r = 0; r < 4; ++r) red[r][t] = acc[r];
    }
    __syncthreads();
    if (!half) {
        #pragma unroll
        for (int r = 0; r < 4; ++r) O[(r0 + r) * H + t] = exp2_fast(acc[r] + red[r][t]);
    }
}

// ---- fully fused: scores (reg) + softmax + context + MLP -----------------
// tanh(a+b) = 1 - 2/(1 + Ea*Eb); score = -2 * sum_h ws[h]/(1+Ea*Eb)
// (softmax-invariant constant dropped). One block per 4 attenders.
#define PAIR(eax, eay, ebx, eby, wx, wy, accv)                 \
    { float q0 = fmaf(eax, ebx, 1.0f);                         \
      float q1 = fmaf(eay, eby, 1.0f);                         \
      float nn = wx * q1; nn = fmaf(wy, q0, nn);               \
      float rr = __builtin_amdgcn_rcpf(q0 * q1);               \
      accv = fmaf(nn, rr, accv); }

#define TMD 4
__device__ __forceinline__ void reduce4(float v[TMD], bool domax, float (*scr)[TMD]) {
    #pragma unroll
    for (int off = 32; off > 0; off >>= 1) {
        #pragma unroll
        for (int j = 0; j < TMD; ++j) {
            float o = __shfl_xor(v[j], off, 64);
            v[j] = domax ? fmaxf(v[j], o) : (v[j] + o);
        }
    }
    int wv = threadIdx.x >> 6;
    if ((threadIdx.x & 63) == 0) {
        #pragma unroll
        for (int j = 0; j < TMD; ++j) scr[wv][j] = v[j];
    }
    __syncthreads();
    #pragma unroll
    for (int j = 0; j < TMD; ++j) {
        float r = scr[0][j];
        #pragma unroll
        for (int i = 1; i < 16; ++i) r = domax ? fmaxf(r, scr[i][j]) : (r + scr[i][j]);
        v[j] = r;
    }
    __syncthreads();
}

__global__ __launch_bounds__(1024) void k_fused(const float* __restrict__ EA_s,
                                                const float* __restrict__ EB_s,
                                                const float* __restrict__ ws_s,
                                                const float* __restrict__ EA_e,
                                                const float* __restrict__ EB_e,
                                                const float* __restrict__ ws_e,
                                                const float* __restrict__ stmts,
                                                const float* __restrict__ eres,
                                                const float* __restrict__ attender,
                                                const float* __restrict__ WT_lin,
                                                const float* __restrict__ b_lin,
                                                const float* __restrict__ W_coh,
                                                const float* __restrict__ b_coh,
                                                float* __restrict__ out) {
    __shared__ float EAl[1024][17];     // 68KB h-chunk stage, +1 pad: b128 ok
    __shared__ float Bs[TMD][H];        // EB_s rows (broadcast source)
    __shared__ float Be[TMD][H];        // EB_e rows
    __shared__ float sc_e[512][TMD];    // e-score redistribution
    __shared__ float wls[1024][TMD];
    __shared__ float part[8][TMD][H];
    __shared__ float feats[TMD][3 * H];
    __shared__ float scr[16][TMD];
    __shared__ float redv[512];
    __shared__ float red8[8];

    int m0  = blockIdx.x * TMD;
    int tid = threadIdx.x;
    int h   = tid & (H - 1);
    int g   = tid >> 7;

    if (tid < 512) Bs[tid >> 7][tid & 127] = EB_s[(size_t)(m0 + (tid >> 7)) * H + (tid & 127)];
    else { int t2 = tid - 512; Be[t2 >> 7][t2 & 127] = EB_e[(size_t)(m0 + (t2 >> 7)) * H + (t2 & 127)]; }
    if (tid < TMD * H) feats[tid >> 7][tid & 127] = attender[(size_t)(m0 + (tid >> 7)) * H + (tid & 127)];

    int r0 = tid >> 2;            // staging: 4 rows/thread, 256 apart
    int p0 = (tid & 3) * 4;

    // ---------------- phase A: s-scores (n = tid) ----------------
    float accs[TMD] = {0.f, 0.f, 0.f, 0.f};
    {
        const float* base = EA_s + p0;
        float4 v0 = *(const float4*)(base + (size_t)(r0      ) * H);
        float4 v1 = *(const float4*)(base + (size_t)(r0 + 256) * H);
        float4 v2 = *(const float4*)(base + (size_t)(r0 + 512) * H);
        float4 v3 = *(const float4*)(base + (size_t)(r0 + 768) * H);
        for (int ch = 0; ch < 8; ++ch) {
            int h0 = ch * 16;
            __syncthreads();                 // prev readers done (ch=0: Bs staged)
            *(float4*)&EAl[r0      ][p0] = v0;
            *(float4*)&EAl[r0 + 256][p0] = v1;
            *(float4*)&EAl[r0 + 512][p0] = v2;
            *(float4*)&EAl[r0 + 768][p0] = v3;
            __syncthreads();
            if (ch < 7) {
                int off = h0 + 16;
                v0 = *(const float4*)(base + (size_t)(r0      ) * H + off);
                v1 = *(const float4*)(base + (size_t)(r0 + 256) * H + off);
                v2 = *(const float4*)(base + (size_t)(r0 + 512) * H + off);
                v3 = *(const float4*)(base + (size_t)(r0 + 768) * H + off);
            }
            float wv[16];
            #pragma unroll
            for (int k = 0; k < 16; ++k) wv[k] = ws_s[h0 + k];   // uniform
            float4 a0 = *(const float4*)&EAl[tid][0];
            float4 a1 = *(const float4*)&EAl[tid][4];
            float4 a2 = *(const float4*)&EAl[tid][8];
            float4 a3 = *(const float4*)&EAl[tid][12];
            #pragma unroll
            for (int j = 0; j < TMD; ++j) {
                float4 b0 = *(const float4*)&Bs[j][h0];
                float4 b1 = *(const float4*)&Bs[j][h0 + 4];
                float4 b2 = *(const float4*)&Bs[j][h0 + 8];
                float4 b3 = *(const float4*)&Bs[j][h0 + 12];
                PAIR(a0.x, a0.y, b0.x, b0.y, wv[0],  wv[1],  accs[j]);
                PAIR(a0.z, a0.w, b0.z, b0.w, wv[2],  wv[3],  accs[j]);
                PAIR(a1.x, a1.y, b1.x, b1.y, wv[4],  wv[5],  accs[j]);
                PAIR(a1.z, a1.w, b1.z, b1.w, wv[6],  wv[7],  accs[j]);
                PAIR(a2.x, a2.y, b2.x, b2.y, wv[8],  wv[9],  accs[j]);
                PAIR(a2.z, a2.w, b2.z, b2.w, wv[10], wv[11], accs[j]);
                PAIR(a3.x, a3.y, b3.x, b3.y, wv[12], wv[13], accs[j]);
                PAIR(a3.z, a3.w, b3.z, b3.w, wv[14], wv[15], accs[j]);
            }
        }
    }

    // ---------------- phase B: e-scores (n = tid&511, 2 m's/thread) -------
    float acce[2] = {0.f, 0.f};
    int ne  = tid & 511;
    int jj2 = (tid >> 9) << 1;    // 0 or 2: which m-pair this half handles
    {
        int er0 = tid >> 2;                   // rows er0 (<256) and er0+256
        const float* base = EA_e + p0;
        float4 v0 = *(const float4*)(base + (size_t)(er0      ) * H);
        float4 v1 = *(const float4*)(base + (size_t)(er0 + 256) * H);
        for (int ch = 0; ch < 8; ++ch) {
            int h0 = ch * 16;
            __syncthreads();                 // phase-A / prev-chunk readers done
            *(float4*)&EAl[er0      ][p0] = v0;
            *(float4*)&EAl[er0 + 256][p0] = v1;
            __syncthreads();
            if (ch < 7) {
                int off = h0 + 16;
                v0 = *(const float4*)(base + (size_t)(er0      ) * H + off);
                v1 = *(const float4*)(base + (size_t)(er0 + 256) * H + off);
            }
            float wv[16];
            #pragma unroll
            for (int k = 0; k < 16; ++k) wv[k] = ws_e[h0 + k];
            float4 a0 = *(const float4*)&EAl[ne][0];
            float4 a1 = *(const float4*)&EAl[ne][4];
            float4 a2 = *(const float4*)&EAl[ne][8];
            float4 a3 = *(const float4*)&EAl[ne][12];
            #pragma unroll
            for (int j = 0; j < 2; ++j) {
                const float* bp = &Be[jj2 + j][h0];   // wave-uniform row
                float4 b0 = *(const float4*)(bp);
                float4 b1 = *(const float4*)(bp + 4);
                float4 b2 = *(const float4*)(bp + 8);
                float4 b3 = *(const float4*)(bp + 12);
                PAIR(a0.x, a0.y, b0.x, b0.y, wv[0],  wv[1],  acce[j]);
                PAIR(a0.z, a0.w, b0.z, b0.w, wv[2],  wv[3],  acce[j]);
                PAIR(a1.x, a1.y, b1.x, b1.y, wv[4],  wv[5],  acce[j]);
                PAIR(a1.z, a1.w, b1.z, b1.w, wv[6],  wv[7],  acce[j]);
                PAIR(a2.x, a2.y, b2.x, b2.y, wv[8],  wv[9],  acce[j]);
                PAIR(a2.z, a2.w, b2.z, b2.w, wv[10], wv[11], acce[j]);
                PAIR(a3.x, a3.y, b3.x, b3.y, wv[12], wv[13], acce[j]);
                PAIR(a3.z, a3.w, b3.z, b3.w, wv[14], wv[15], acce[j]);
            }
        }
    }
    // redistribute e-scores so thread t holds row t's 4 values
    sc_e[ne][jj2]     = acce[0];
    sc_e[ne][jj2 + 1] = acce[1];
    __syncthreads();

    float vs[TMD], ve[TMD];
    #pragma unroll
    for (int j = 0; j < TMD; ++j) vs[j] = -2.0f * accs[j];
    #pragma unroll
    for (int j = 0; j < TMD; ++j) ve[j] = (tid < 512) ? -2.0f * sc_e[tid][j] : -1e30f;

    // ---------------- softmax stats ----------------
    float mxs[TMD], sm_s[TMD], rz_s[TMD], w_s[TMD];
    #pragma unroll
    for (int j = 0; j < TMD; ++j) mxs[j] = vs[j];
    reduce4(mxs, true, scr);
    #pragma unroll
    for (int j = 0; j < TMD; ++j) { w_s[j] = __expf(vs[j] - mxs[j]); sm_s[j] = w_s[j]; }
    reduce4(sm_s, false, scr);
    #pragma unroll
    for (int j = 0; j < TMD; ++j) rz_s[j] = __builtin_amdgcn_rcpf(sm_s[j]);

    float mxe[TMD], sm_e[TMD], rz_e[TMD], w_e[TMD];
    #pragma unroll
    for (int j = 0; j < TMD; ++j) mxe[j] = ve[j];
    reduce4(mxe, true, scr);
    #pragma unroll
    for (int j = 0; j < TMD; ++j) { w_e[j] = __expf(ve[j] - mxe[j]); sm_e[j] = w_e[j]; }
    reduce4(sm_e, false, scr);
    #pragma unroll
    for (int j = 0; j < TMD; ++j) rz_e[j] = __builtin_amdgcn_rcpf(sm_e[j]);

    // ---------------- ctx_s ----------------
    *(float4*)&wls[tid][0] = make_float4(w_s[0], w_s[1], w_s[2], w_s[3]);
    __syncthreads();
    {
        float acc[TMD] = {0.f, 0.f, 0.f, 0.f};
        const float* Xb = stmts + (size_t)(g * 128) * H + h;
        #pragma unroll 8
        for (int nn = 0; nn < 128; ++nn) {
            float x = Xb[(size_t)nn * H];
            float4 w4 = *(const float4*)&wls[g * 128 + nn][0];
            acc[0] += w4.x * x; acc[1] += w4.y * x;
            acc[2] += w4.z * x; acc[3] += w4.w * x;
        }
        #pragma unroll
        for (int j = 0; j < TMD; ++j) part[g][j][h] = acc[j];
    }
    __syncthreads();
    if (tid < 512) {
        int j = tid >> 7, hh = tid & 127;
        float s = 0.f;
        #pragma unroll
        for (int gg = 0; gg < 8; ++gg) s += part[gg][j][hh];
        feats[j][H + hh] = s * rz_s[j];
    }
    __syncthreads();

    // ---------------- ctx_e ----------------
    *(float4*)&wls[tid][0] = make_float4(w_e[0], w_e[1], w_e[2], w_e[3]);
    __syncthreads();
    {
        float acc[TMD] = {0.f, 0.f, 0.f, 0.f};
        const float* Xb = eres + (size_t)(g * 64) * H + h;
        #pragma unroll 8
        for (int nn = 0; nn < 64; ++nn) {
            float x = Xb[(size_t)nn * H];
            float4 w4 = *(const float4*)&wls[g * 64 + nn][0];
            acc[0] += w4.x * x; acc[1] += w4.y * x;
            acc[2] += w4.z * x; acc[3] += w4.w * x;
        }
        #pragma unroll
        for (int j = 0; j < TMD; ++j) part[g][j][h] = acc[j];
    }
    __syncthreads();
    if (tid < 512) {
        int j = tid >> 7, hh = tid & 127;
        float s = 0.f;
        #pragma unroll
        for (int gg = 0; gg < 8; ++gg) s += part[gg][j][hh];
        feats[j][2 * H + hh] = s * rz_e[j];
    }
    __syncthreads();

    // ---------------- final MLP + coherence ----------------
    {
        int a    = tid & 127;
        int jm   = (tid >> 7) & 3;
        int half = tid >> 9;
        float acc = half ? 0.f : b_lin[a];
        int k0 = half * 192;
        #pragma unroll 8
        for (int k = k0; k < k0 + 192; ++k)
            acc += feats[jm][k] * WT_lin[k * H + a];
        if (half) redv[tid & 511] = acc;
        __syncthreads();
        if (!half) {
            acc += redv[tid];
            float v = fast_tanh(acc) * W_coh[a];
            #pragma unroll
            for (int off = 32; off > 0; off >>= 1) v += __shfl_down(v, off, 64);
            if ((tid & 63) == 0) red8[tid >> 6] = v;
        }
        __syncthreads();
        if (tid < TMD) out[m0 + tid] = red8[2 * tid] + red8[2 * tid + 1] + b_coh[0];
    }
}

extern "C" void kernel_launch(void* const* d_in, const int* in_sizes, int n_in,
                              void* d_out, int out_size, void* d_ws, size_t ws_size,
                              hipStream_t stream) {
    const float* stmts    = (const float*)d_in[0];
    const float* eres     = (const float*)d_in[1];
    const float* attender = (const float*)d_in[2];
    const float* Wc_s     = (const float*)d_in[3];
    const float* bc_s     = (const float*)d_in[4];
    const float* ws_s     = (const float*)d_in[5];
    const float* Wc_e     = (const float*)d_in[7];
    const float* bc_e     = (const float*)d_in[8];
    const float* ws_e     = (const float*)d_in[9];
    const float* W_lin    = (const float*)d_in[11];
    const float* b_lin    = (const float*)d_in[12];
    const float* W_coh    = (const float*)d_in[13];
    const float* b_coh    = (const float*)d_in[14];
    float* out = (float*)d_out;

    float* ws    = (float*)d_ws;
    float* WT_s1 = ws;
    float* WT_s2 = WT_s1 + H * H;
    float* WT_e1 = WT_s2 + H * H;
    float* WT_e2 = WT_e1 + H * H;
    float* WT_li = WT_e2 + H * H;             // 384*128
    float* EA_s  = WT_li + 3 * H * H;
    float* EB_s  = EA_s + NS * H;
    float* EA_e  = EB_s + M * H;
    float* EB_e  = EA_e + NE * H;

    k_tr<<<448, 256, 0, stream>>>(Wc_s, Wc_e, W_lin, WT_s1, WT_s2, WT_e1, WT_e2, WT_li);
    k_proj<<<896, 256, 0, stream>>>(stmts, eres, attender, WT_s1, WT_s2, WT_e1, WT_e2,
                                    bc_s, bc_e, EA_s, EB_s, EA_e, EB_e);
    k_fused<<<M / TMD, 1024, 0, stream>>>(EA_s, EB_s, ws_s, EA_e, EB_e, ws_e,
                                          stmts, eres, attender, WT_li,
                                          b_lin, W_coh, b_coh, out);
}

// Round 13
// 95.881 us; speedup vs baseline: 1.0536x; 1.0536x over previous
//
#include <hip/hip_runtime.h>
#include <math.h>

#define H   128
#define NS  1024
#define NE  512
#define M   1024
#define K2  2.8853900817779268f   // 2*log2(e): tanh(x) = 1 - 2/(1+exp2(K2*x))

__device__ __forceinline__ float exp2_fast(float x) {
#if __has_builtin(__builtin_amdgcn_exp2f)
    return __builtin_amdgcn_exp2f(x);
#else
    return __expf(x * 0.6931471805599453f);
#endif
}

__device__ __forceinline__ float fast_tanh(float x) {
    float e = __expf(2.0f * x);
    float r = __builtin_amdgcn_rcpf(1.0f + e);
    return 1.0f - 2.0f * r;
}

// ---- transpose (+K2 scale) the weight matrices ---------------------------
__global__ __launch_bounds__(256) void k_tr(const float* __restrict__ Wc_s,
                                            const float* __restrict__ Wc_e,
                                            const float* __restrict__ W_lin,
                                            float* __restrict__ WT_s1, float* __restrict__ WT_s2,
                                            float* __restrict__ WT_e1, float* __restrict__ WT_e2,
                                            float* __restrict__ WT_lin) {
    int idx = blockIdx.x * 256 + threadIdx.x;
    if (idx < 65536) {
        int t = idx >> 14, r = idx & 16383, k = r >> 7, hh = r & 127;
        const float* src = (t < 2) ? Wc_s : Wc_e;
        int off = (t & 1) * H;
        float v = K2 * src[hh * 256 + off + k];
        float* dst = (t == 0) ? WT_s1 : (t == 1) ? WT_s2 : (t == 2) ? WT_e1 : WT_e2;
        dst[r] = v;
    } else {
        int j2 = idx - 65536;             // [0, 49152)
        int k = j2 >> 7, a = j2 & 127;
        WT_lin[j2] = W_lin[a * 384 + k];
    }
}

// ---- projections -> exp2 domain ------------------------------------------
// A-path (blocks 0..95): 16 rows/block, output TRANSPOSED EAT[h][n]
// B-path (blocks 96..607): 4 rows/block, normal layout EB[m][h]
__global__ __launch_bounds__(256) void k_proj(const float* __restrict__ stmts,
                                              const float* __restrict__ eres,
                                              const float* __restrict__ attender,
                                              const float* __restrict__ WT_s1,
                                              const float* __restrict__ WT_s2,
                                              const float* __restrict__ WT_e1,
                                              const float* __restrict__ WT_e2,
                                              const float* __restrict__ bc_s,
                                              const float* __restrict__ bc_e,
                                              float* __restrict__ EAT_s, float* __restrict__ EB_s,
                                              float* __restrict__ EAT_e, float* __restrict__ EB_e) {
    __shared__ float xr[16][H];
    __shared__ float red[16][H];
    int b   = blockIdx.x;
    int tid = threadIdx.x;
    int t    = tid & 127;
    int half = tid >> 7;

    if (b < 96) {
        // ---- transposed A path ----
        const float *X, *WT, *bias; float* OT; int r0, N;
        if (b < 64) { X = stmts; WT = WT_s1; bias = bc_s; OT = EAT_s; r0 = b * 16;        N = NS; }
        else        { X = eres;  WT = WT_e1; bias = bc_e; OT = EAT_e; r0 = (b - 64) * 16; N = NE; }
        for (int i = tid; i < 16 * H; i += 256) xr[i >> 7][i & 127] = X[(r0 + (i >> 7)) * H + (i & 127)];
        __syncthreads();
        float b0 = (half == 0) ? K2 * bias[t] : 0.0f;
        float acc[16];
        #pragma unroll
        for (int r = 0; r < 16; ++r) acc[r] = b0;
        int k0 = half * 64;
        #pragma unroll 4
        for (int k = k0; k < k0 + 64; ++k) {
            float wv = WT[k * H + t];
            #pragma unroll
            for (int r = 0; r < 16; ++r) acc[r] += xr[r][k] * wv;
        }
        if (half) {
            #pragma unroll
            for (int r = 0; r < 16; ++r) red[r][t] = acc[r];
        }
        __syncthreads();   // also: all xr reads done, safe to overwrite
        if (!half) {
            #pragma unroll
            for (int r = 0; r < 16; ++r) xr[r][t] = exp2_fast(acc[r] + red[r][t]);
        }
        __syncthreads();
        {
            int hh  = tid >> 1;           // 0..127
            int seg = (tid & 1) * 8;      // 0 or 8
            float4 v0 = make_float4(xr[seg + 0][hh], xr[seg + 1][hh], xr[seg + 2][hh], xr[seg + 3][hh]);
            float4 v1 = make_float4(xr[seg + 4][hh], xr[seg + 5][hh], xr[seg + 6][hh], xr[seg + 7][hh]);
            *(float4*)(OT + (size_t)hh * N + r0 + seg)     = v0;
            *(float4*)(OT + (size_t)hh * N + r0 + seg + 4) = v1;
        }
    } else {
        // ---- normal B path (attender projections) ----
        int b2 = b - 96;
        const float* WT = (b2 < 256) ? WT_s2 : WT_e2;
        float* O        = (b2 < 256) ? EB_s : EB_e;
        int r0          = (b2 & 255) * 4;
        float* xf = &xr[0][0];
        xf[tid]       = attender[r0 * H + tid];
        xf[tid + 256] = attender[r0 * H + 256 + tid];
        __syncthreads();
        float acc[4] = {0.f, 0.f, 0.f, 0.f};
        int k0 = half * 64;
        #pragma unroll 8
        for (int k = k0; k < k0 + 64; ++k) {
            float wv = WT[k * H + t];
            #pragma unroll
            for (int r = 0; r < 4; ++r) acc[r] += xr[r >> 2][((r & 3) << 7) + k] * wv;  // xr[0..3][k] flat
        }
        // note: rows are xr flat [4][128] == xf[r*128+k]
        if (half) {
            #pragma unroll
            for (int r = 0; r < 4; ++r) red[r][t] = acc[r];
        }
        __syncthreads();
        if (!half) {
            #pragma unroll
            for (int r = 0; r < 4; ++r) O[(r0 + r) * H + t] = exp2_fast(acc[r] + red[r][t]);
        }
    }
}

// ---- fully fused: scores (coalesced EAT reads, no barriers) + softmax +
//      context + MLP.  score = -2 * sum_h ws[h]/(1+Ea*Eb)  (const dropped)
#define PAIR(eax, eay, ebx, eby, wx, wy, accv)                 \
    { float q0 = fmaf(eax, ebx, 1.0f);                         \
      float q1 = fmaf(eay, eby, 1.0f);                         \
      float nn = wx * q1; nn = fmaf(wy, q0, nn);               \
      float rr = __builtin_amdgcn_rcpf(q0 * q1);               \
      accv = fmaf(nn, rr, accv); }

#define TMD 4
__device__ __forceinline__ void reduce4(float v[TMD], bool domax, float (*scr)[TMD]) {
    #pragma unroll
    for (int off = 32; off > 0; off >>= 1) {
        #pragma unroll
        for (int j = 0; j < TMD; ++j) {
            float o = __shfl_xor(v[j], off, 64);
            v[j] = domax ? fmaxf(v[j], o) : (v[j] + o);
        }
    }
    int wv = threadIdx.x >> 6;
    if ((threadIdx.x & 63) == 0) {
        #pragma unroll
        for (int j = 0; j < TMD; ++j) scr[wv][j] = v[j];
    }
    __syncthreads();
    #pragma unroll
    for (int j = 0; j < TMD; ++j) {
        float r = scr[0][j];
        #pragma unroll
        for (int i = 1; i < 16; ++i) r = domax ? fmaxf(r, scr[i][j]) : (r + scr[i][j]);
        v[j] = r;
    }
    __syncthreads();
}

__global__ __launch_bounds__(1024) void k_fused(const float* __restrict__ EAT_s,
                                                const float* __restrict__ EB_s,
                                                const float* __restrict__ ws_s,
                                                const float* __restrict__ EAT_e,
                                                const float* __restrict__ EB_e,
                                                const float* __restrict__ ws_e,
                                                const float* __restrict__ stmts,
                                                const float* __restrict__ eres,
                                                const float* __restrict__ attender,
                                                const float* __restrict__ WT_lin,
                                                const float* __restrict__ b_lin,
                                                const float* __restrict__ W_coh,
                                                const float* __restrict__ b_coh,
                                                float* __restrict__ out) {
    __shared__ float Bs[TMD][H];        // EB_s rows (broadcast)
    __shared__ float Be[TMD][H];
    __shared__ float sc_e[512][5];      // +1 pad: conflict-free
    __shared__ float wls[1024][TMD];
    __shared__ float part[8][TMD][H];
    __shared__ float feats[TMD][3 * H];
    __shared__ float scr[16][TMD];
    __shared__ float redv[512];
    __shared__ float red8[8];

    int m0  = blockIdx.x * TMD;
    int tid = threadIdx.x;
    int h   = tid & (H - 1);
    int g   = tid >> 7;

    if (tid < 512) Bs[tid >> 7][tid & 127] = EB_s[(size_t)(m0 + (tid >> 7)) * H + (tid & 127)];
    else { int t2 = tid - 512; Be[t2 >> 7][t2 & 127] = EB_e[(size_t)(m0 + (t2 >> 7)) * H + (t2 & 127)]; }
    if (tid < TMD * H) feats[tid >> 7][tid & 127] = attender[(size_t)(m0 + (tid >> 7)) * H + (tid & 127)];
    __syncthreads();

    // ---------------- phase A: s-scores (n = tid), barrier-free ----------
    float accs[TMD] = {0.f, 0.f, 0.f, 0.f};
    #pragma unroll 2
    for (int h0 = 0; h0 < H; h0 += 16) {
        float a[16], wv[16];
        #pragma unroll
        for (int k = 0; k < 16; ++k) a[k] = EAT_s[(size_t)(h0 + k) * NS + tid];
        #pragma unroll
        for (int k = 0; k < 16; ++k) wv[k] = ws_s[h0 + k];   // uniform -> s_load
        #pragma unroll
        for (int j = 0; j < TMD; ++j) {
            float4 b0 = *(const float4*)&Bs[j][h0];
            float4 b1 = *(const float4*)&Bs[j][h0 + 4];
            float4 b2 = *(const float4*)&Bs[j][h0 + 8];
            float4 b3 = *(const float4*)&Bs[j][h0 + 12];
            PAIR(a[0],  a[1],  b0.x, b0.y, wv[0],  wv[1],  accs[j]);
            PAIR(a[2],  a[3],  b0.z, b0.w, wv[2],  wv[3],  accs[j]);
            PAIR(a[4],  a[5],  b1.x, b1.y, wv[4],  wv[5],  accs[j]);
            PAIR(a[6],  a[7],  b1.z, b1.w, wv[6],  wv[7],  accs[j]);
            PAIR(a[8],  a[9],  b2.x, b2.y, wv[8],  wv[9],  accs[j]);
            PAIR(a[10], a[11], b2.z, b2.w, wv[10], wv[11], accs[j]);
            PAIR(a[12], a[13], b3.x, b3.y, wv[12], wv[13], accs[j]);
            PAIR(a[14], a[15], b3.z, b3.w, wv[14], wv[15], accs[j]);
        }
    }

    // ---------------- phase B: e-scores (row = tid&511, 2 m's) -----------
    float acce[2] = {0.f, 0.f};
    int ne  = tid & 511;
    int jj2 = (tid >> 9) << 1;
    #pragma unroll 2
    for (int h0 = 0; h0 < H; h0 += 16) {
        float a[16], wv[16];
        #pragma unroll
        for (int k = 0; k < 16; ++k) a[k] = EAT_e[(size_t)(h0 + k) * NE + ne];
        #pragma unroll
        for (int k = 0; k < 16; ++k) wv[k] = ws_e[h0 + k];
        #pragma unroll
        for (int j = 0; j < 2; ++j) {
            const float* bp = &Be[jj2 + j][h0];
            float4 b0 = *(const float4*)(bp);
            float4 b1 = *(const float4*)(bp + 4);
            float4 b2 = *(const float4*)(bp + 8);
            float4 b3 = *(const float4*)(bp + 12);
            PAIR(a[0],  a[1],  b0.x, b0.y, wv[0],  wv[1],  acce[j]);
            PAIR(a[2],  a[3],  b0.z, b0.w, wv[2],  wv[3],  acce[j]);
            PAIR(a[4],  a[5],  b1.x, b1.y, wv[4],  wv[5],  acce[j]);
            PAIR(a[6],  a[7],  b1.z, b1.w, wv[6],  wv[7],  acce[j]);
            PAIR(a[8],  a[9],  b2.x, b2.y, wv[8],  wv[9],  acce[j]);
            PAIR(a[10], a[11], b2.z, b2.w, wv[10], wv[11], acce[j]);
            PAIR(a[12], a[13], b3.x, b3.y, wv[12], wv[13], acce[j]);
            PAIR(a[14], a[15], b3.z, b3.w, wv[14], wv[15], acce[j]);
        }
    }
    sc_e[ne][jj2]     = acce[0];
    sc_e[ne][jj2 + 1] = acce[1];
    __syncthreads();

    float vs[TMD], ve[TMD];
    #pragma unroll
    for (int j = 0; j < TMD; ++j) vs[j] = -2.0f * accs[j];
    #pragma unroll
    for (int j = 0; j < TMD; ++j) ve[j] = (tid < 512) ? -2.0f * sc_e[tid][j] : -1e30f;

    // ---------------- softmax stats ----------------
    float mxs[TMD], sm_s[TMD], rz_s[TMD], w_s[TMD];
    #pragma unroll
    for (int j = 0; j < TMD; ++j) mxs[j] = vs[j];
    reduce4(mxs, true, scr);
    #pragma unroll
    for (int j = 0; j < TMD; ++j) { w_s[j] = __expf(vs[j] - mxs[j]); sm_s[j] = w_s[j]; }
    reduce4(sm_s, false, scr);
    #pragma unroll
    for (int j = 0; j < TMD; ++j) rz_s[j] = __builtin_amdgcn_rcpf(sm_s[j]);

    float mxe[TMD], sm_e[TMD], rz_e[TMD], w_e[TMD];
    #pragma unroll
    for (int j = 0; j < TMD; ++j) mxe[j] = ve[j];
    reduce4(mxe, true, scr);
    #pragma unroll
    for (int j = 0; j < TMD; ++j) { w_e[j] = __expf(ve[j] - mxe[j]); sm_e[j] = w_e[j]; }
    reduce4(sm_e, false, scr);
    #pragma unroll
    for (int j = 0; j < TMD; ++j) rz_e[j] = __builtin_amdgcn_rcpf(sm_e[j]);

    // ---------------- ctx_s ----------------
    *(float4*)&wls[tid][0] = make_float4(w_s[0], w_s[1], w_s[2], w_s[3]);
    __syncthreads();
    {
        float acc[TMD] = {0.f, 0.f, 0.f, 0.f};
        const float* Xb = stmts + (size_t)(g * 128) * H + h;
        #pragma unroll 8
        for (int nn = 0; nn < 128; ++nn) {
            float x = Xb[(size_t)nn * H];
            float4 w4 = *(const float4*)&wls[g * 128 + nn][0];
            acc[0] += w4.x * x; acc[1] += w4.y * x;
            acc[2] += w4.z * x; acc[3] += w4.w * x;
        }
        #pragma unroll
        for (int j = 0; j < TMD; ++j) part[g][j][h] = acc[j];
    }
    __syncthreads();
    if (tid < 512) {
        int j = tid >> 7, hh = tid & 127;
        float s = 0.f;
        #pragma unroll
        for (int gg = 0; gg < 8; ++gg) s += part[gg][j][hh];
        feats[j][H + hh] = s * rz_s[j];
    }
    __syncthreads();

    // ---------------- ctx_e ----------------
    *(float4*)&wls[tid][0] = make_float4(w_e[0], w_e[1], w_e[2], w_e[3]);
    __syncthreads();
    {
        float acc[TMD] = {0.f, 0.f, 0.f, 0.f};
        const float* Xb = eres + (size_t)(g * 64) * H + h;
        #pragma unroll 8
        for (int nn = 0; nn < 64; ++nn) {
            float x = Xb[(size_t)nn * H];
            float4 w4 = *(const float4*)&wls[g * 64 + nn][0];
            acc[0] += w4.x * x; acc[1] += w4.y * x;
            acc[2] += w4.z * x; acc[3] += w4.w * x;
        }
        #pragma unroll
        for (int j = 0; j < TMD; ++j) part[g][j][h] = acc[j];
    }
    __syncthreads();
    if (tid < 512) {
        int j = tid >> 7, hh = tid & 127;
        float s = 0.f;
        #pragma unroll
        for (int gg = 0; gg < 8; ++gg) s += part[gg][j][hh];
        feats[j][2 * H + hh] = s * rz_e[j];
    }
    __syncthreads();

    // ---------------- final MLP + coherence ----------------
    {
        int a    = tid & 127;
        int jm   = (tid >> 7) & 3;
        int half = tid >> 9;
        float acc = half ? 0.f : b_lin[a];
        int k0 = half * 192;
        #pragma unroll 8
        for (int k = k0; k < k0 + 192; ++k)
            acc += feats[jm][k] * WT_lin[k * H + a];
        if (half) redv[tid & 511] = acc;
        __syncthreads();
        if (!half) {
            acc += redv[tid];
            float v = fast_tanh(acc) * W_coh[a];
            #pragma unroll
            for (int off = 32; off > 0; off >>= 1) v += __shfl_down(v, off, 64);
            if ((tid & 63) == 0) red8[tid >> 6] = v;
        }
        __syncthreads();
        if (tid < TMD) out[m0 + tid] = red8[2 * tid] + red8[2 * tid + 1] + b_coh[0];
    }
}

extern "C" void kernel_launch(void* const* d_in, const int* in_sizes, int n_in,
                              void* d_out, int out_size, void* d_ws, size_t ws_size,
                              hipStream_t stream) {
    const float* stmts    = (const float*)d_in[0];
    const float* eres     = (const float*)d_in[1];
    const float* attender = (const float*)d_in[2];
    const float* Wc_s     = (const float*)d_in[3];
    const float* bc_s     = (const float*)d_in[4];
    const float* ws_s     = (const float*)d_in[5];
    const float* Wc_e     = (const float*)d_in[7];
    const float* bc_e     = (const float*)d_in[8];
    const float* ws_e     = (const float*)d_in[9];
    const float* W_lin    = (const float*)d_in[11];
    const float* b_lin    = (const float*)d_in[12];
    const float* W_coh    = (const float*)d_in[13];
    const float* b_coh    = (const float*)d_in[14];
    float* out = (float*)d_out;

    float* ws    = (float*)d_ws;
    float* WT_s1 = ws;
    float* WT_s2 = WT_s1 + H * H;
    float* WT_e1 = WT_s2 + H * H;
    float* WT_e2 = WT_e1 + H * H;
    float* WT_li = WT_e2 + H * H;             // 384*128
    float* EAT_s = WT_li + 3 * H * H;         // transposed [H][NS]
    float* EB_s  = EAT_s + NS * H;
    float* EAT_e = EB_s + M * H;              // transposed [H][NE]
    float* EB_e  = EAT_e + NE * H;

    k_tr<<<448, 256, 0, stream>>>(Wc_s, Wc_e, W_lin, WT_s1, WT_s2, WT_e1, WT_e2, WT_li);
    k_proj<<<608, 256, 0, stream>>>(stmts, eres, attender, WT_s1, WT_s2, WT_e1, WT_e2,
                                    bc_s, bc_e, EAT_s, EB_s, EAT_e, EB_e);
    k_fused<<<M / TMD, 1024, 0, stream>>>(EAT_s, EB_s, ws_s, EAT_e, EB_e, ws_e,
                                          stmts, eres, attender, WT_li,
                                          b_lin, W_coh, b_coh, out);
}

// Round 15
// 67.749 us; speedup vs baseline: 1.4912x; 1.4152x over previous
//
#include <hip/hip_runtime.h>
#include <math.h>

#define H   128
#define NS  1024
#define NE  512
#define M   1024
#define K2  2.8853900817779268f   // 2*log2(e): tanh(x) = 1 - 2/(1+exp2(K2*x))

__device__ __forceinline__ float exp2_fast(float x) {
#if __has_builtin(__builtin_amdgcn_exp2f)
    return __builtin_amdgcn_exp2f(x);
#else
    return __expf(x * 0.6931471805599453f);
#endif
}

__device__ __forceinline__ float fast_tanh(float x) {
    float e = __expf(2.0f * x);
    float r = __builtin_amdgcn_rcpf(1.0f + e);
    return 1.0f - 2.0f * r;
}

// ---- transpose (+K2 scale) the weight matrices ---------------------------
__global__ __launch_bounds__(256) void k_tr(const float* __restrict__ Wc_s,
                                            const float* __restrict__ Wc_e,
                                            const float* __restrict__ W_lin,
                                            float* __restrict__ WT_s1, float* __restrict__ WT_s2,
                                            float* __restrict__ WT_e1, float* __restrict__ WT_e2,
                                            float* __restrict__ WT_lin) {
    int idx = blockIdx.x * 256 + threadIdx.x;
    if (idx < 65536) {
        int t = idx >> 14, r = idx & 16383, k = r >> 7, hh = r & 127;
        const float* src = (t < 2) ? Wc_s : Wc_e;
        int off = (t & 1) * H;
        float v = K2 * src[hh * 256 + off + k];
        float* dst = (t == 0) ? WT_s1 : (t == 1) ? WT_s2 : (t == 2) ? WT_e1 : WT_e2;
        dst[r] = v;
    } else {
        int j2 = idx - 65536;             // [0, 49152)
        int k = j2 >> 7, a = j2 & 127;
        WT_lin[j2] = W_lin[a * 384 + k];
    }
}

// ---- projections -> exp2 domain ------------------------------------------
// A-path (blocks 0..95): 16 rows/block, output TRANSPOSED EAT[h][n]
// B-path (blocks 96..607): 4 rows/block, normal layout EB[m][h]
__global__ __launch_bounds__(256) void k_proj(const float* __restrict__ stmts,
                                              const float* __restrict__ eres,
                                              const float* __restrict__ attender,
                                              const float* __restrict__ WT_s1,
                                              const float* __restrict__ WT_s2,
                                              const float* __restrict__ WT_e1,
                                              const float* __restrict__ WT_e2,
                                              const float* __restrict__ bc_s,
                                              const float* __restrict__ bc_e,
                                              float* __restrict__ EAT_s, float* __restrict__ EB_s,
                                              float* __restrict__ EAT_e, float* __restrict__ EB_e) {
    __shared__ float xr[16][H];
    __shared__ float red[16][H];
    int b   = blockIdx.x;
    int tid = threadIdx.x;
    int t    = tid & 127;
    int half = tid >> 7;

    if (b < 96) {
        const float *X, *WT, *bias; float* OT; int r0, N;
        if (b < 64) { X = stmts; WT = WT_s1; bias = bc_s; OT = EAT_s; r0 = b * 16;        N = NS; }
        else        { X = eres;  WT = WT_e1; bias = bc_e; OT = EAT_e; r0 = (b - 64) * 16; N = NE; }
        for (int i = tid; i < 16 * H; i += 256) xr[i >> 7][i & 127] = X[(r0 + (i >> 7)) * H + (i & 127)];
        __syncthreads();
        float b0 = (half == 0) ? K2 * bias[t] : 0.0f;
        float acc[16];
        #pragma unroll
        for (int r = 0; r < 16; ++r) acc[r] = b0;
        int k0 = half * 64;
        #pragma unroll 4
        for (int k = k0; k < k0 + 64; ++k) {
            float wv = WT[k * H + t];
            #pragma unroll
            for (int r = 0; r < 16; ++r) acc[r] += xr[r][k] * wv;
        }
        if (half) {
            #pragma unroll
            for (int r = 0; r < 16; ++r) red[r][t] = acc[r];
        }
        __syncthreads();
        if (!half) {
            #pragma unroll
            for (int r = 0; r < 16; ++r) xr[r][t] = exp2_fast(acc[r] + red[r][t]);
        }
        __syncthreads();
        {
            int hh  = tid >> 1;
            int seg = (tid & 1) * 8;
            float4 v0 = make_float4(xr[seg + 0][hh], xr[seg + 1][hh], xr[seg + 2][hh], xr[seg + 3][hh]);
            float4 v1 = make_float4(xr[seg + 4][hh], xr[seg + 5][hh], xr[seg + 6][hh], xr[seg + 7][hh]);
            *(float4*)(OT + (size_t)hh * N + r0 + seg)     = v0;
            *(float4*)(OT + (size_t)hh * N + r0 + seg + 4) = v1;
        }
    } else {
        int b2 = b - 96;
        const float* WT = (b2 < 256) ? WT_s2 : WT_e2;
        float* O        = (b2 < 256) ? EB_s : EB_e;
        int r0          = (b2 & 255) * 4;
        float* xf = &xr[0][0];
        xf[tid]       = attender[r0 * H + tid];
        xf[tid + 256] = attender[r0 * H + 256 + tid];
        __syncthreads();
        float acc[4] = {0.f, 0.f, 0.f, 0.f};
        int k0 = half * 64;
        #pragma unroll 8
        for (int k = k0; k < k0 + 64; ++k) {
            float wv = WT[k * H + t];
            #pragma unroll
            for (int r = 0; r < 4; ++r) acc[r] += xf[r * H + k] * wv;
        }
        if (half) {
            #pragma unroll
            for (int r = 0; r < 4; ++r) red[r][t] = acc[r];
        }
        __syncthreads();
        if (!half) {
            #pragma unroll
            for (int r = 0; r < 4; ++r) O[(r0 + r) * H + t] = exp2_fast(acc[r] + red[r][t]);
        }
    }
}

// ---- scores + softmax weights --------------------------------------------
// score = -2 * sum_h ws[h]/(1+Ea*Eb)   (softmax-invariant const dropped)
// Block: 4 m's x 512 threads. s-blocks: 2 n-rows/thread; e-blocks: 1 row.
// Writes w = exp(s - max) (nontemporal) and rz[m] = 1/sum.
#define PAIR(eax, eay, ebx, eby, wx, wy, accv)                 \
    { float q0 = fmaf(eax, ebx, 1.0f);                         \
      float q1 = fmaf(eay, eby, 1.0f);                         \
      float nn = wx * q1; nn = fmaf(wy, q0, nn);               \
      float rr = __builtin_amdgcn_rcpf(q0 * q1);               \
      accv = fmaf(nn, rr, accv); }

__global__ __launch_bounds__(512, 4) void k_score_w(const float* __restrict__ EAT_s,
                                                    const float* __restrict__ EB_s,
                                                    const float* __restrict__ ws_s,
                                                    const float* __restrict__ EAT_e,
                                                    const float* __restrict__ EB_e,
                                                    const float* __restrict__ ws_e,
                                                    float* __restrict__ w_s, float* __restrict__ rz_s,
                                                    float* __restrict__ w_e, float* __restrict__ rz_e) {
    __shared__ float Bs[4][H];
    __shared__ float scrm[8][4], scrs[8][4];
    int b = blockIdx.x;                   // 0..511
    bool is_e = (b >= 256);
    int m0 = (is_e ? (b - 256) : b) * 4;
    const float* EAT = is_e ? EAT_e : EAT_s;
    const float* EB  = is_e ? EB_e  : EB_s;
    const float* wsv = is_e ? ws_e  : ws_s;
    float* wout      = is_e ? w_e   : w_s;
    float* rzout     = is_e ? rz_e  : rz_s;
    int N    = is_e ? NE : NS;
    int ROWS = is_e ? 1 : 2;
    int t = threadIdx.x;

    Bs[t >> 7][t & 127] = EB[(size_t)(m0 + (t >> 7)) * H + (t & 127)];
    __syncthreads();

    float acc[2][4] = {{0.f,0.f,0.f,0.f},{0.f,0.f,0.f,0.f}};
    for (int h0 = 0; h0 < H; h0 += 8) {
        float a[2][8];
        #pragma unroll
        for (int i = 0; i < 2; ++i)
            if (i < ROWS) {
                #pragma unroll
                for (int k = 0; k < 8; ++k)
                    a[i][k] = EAT[(size_t)(h0 + k) * N + t + 512 * i];
            }
        float wv[8];
        #pragma unroll
        for (int k = 0; k < 8; ++k) wv[k] = wsv[h0 + k];   // uniform -> s_load
        #pragma unroll
        for (int mj = 0; mj < 4; ++mj) {
            float bv[8];
            #pragma unroll
            for (int k = 0; k < 8; ++k) bv[k] = Bs[mj][h0 + k];   // broadcast
            #pragma unroll
            for (int i = 0; i < 2; ++i)
                if (i < ROWS) {
                    PAIR(a[i][0], a[i][1], bv[0], bv[1], wv[0], wv[1], acc[i][mj]);
                    PAIR(a[i][2], a[i][3], bv[2], bv[3], wv[2], wv[3], acc[i][mj]);
                    PAIR(a[i][4], a[i][5], bv[4], bv[5], wv[4], wv[5], acc[i][mj]);
                    PAIR(a[i][6], a[i][7], bv[6], bv[7], wv[6], wv[7], acc[i][mj]);
                }
        }
    }

    // ---- block-wide max & sum per mj ----
    int wave = t >> 6;
    float mx[4];
    for (int mj = 0; mj < 4; ++mj) {
        float v = -2.0f * acc[0][mj];
        if (ROWS > 1) v = fmaxf(v, -2.0f * acc[1][mj]);
        mx[mj] = v;
    }
    #pragma unroll
    for (int off = 32; off > 0; off >>= 1)
        for (int mj = 0; mj < 4; ++mj) mx[mj] = fmaxf(mx[mj], __shfl_xor(mx[mj], off, 64));
    if ((t & 63) == 0) {
        for (int mj = 0; mj < 4; ++mj) scrm[wave][mj] = mx[mj];
    }
    __syncthreads();
    for (int mj = 0; mj < 4; ++mj) {
        float r = scrm[0][mj];
        for (int i = 1; i < 8; ++i) r = fmaxf(r, scrm[i][mj]);
        mx[mj] = r;
    }

    float w0[4], w1[4], sm[4];
    for (int mj = 0; mj < 4; ++mj) {
        w0[mj] = __expf(fmaf(-2.0f, acc[0][mj], -mx[mj]));
        sm[mj] = w0[mj];
        if (ROWS > 1) { w1[mj] = __expf(fmaf(-2.0f, acc[1][mj], -mx[mj])); sm[mj] += w1[mj]; }
    }
    #pragma unroll
    for (int off = 32; off > 0; off >>= 1)
        for (int mj = 0; mj < 4; ++mj) sm[mj] += __shfl_xor(sm[mj], off, 64);
    if ((t & 63) == 0) {
        for (int mj = 0; mj < 4; ++mj) scrs[wave][mj] = sm[mj];
    }
    __syncthreads();

    for (int mj = 0; mj < 4; ++mj) {
        __builtin_nontemporal_store(w0[mj], wout + (size_t)(m0 + mj) * N + t);
        if (ROWS > 1)
            __builtin_nontemporal_store(w1[mj], wout + (size_t)(m0 + mj) * N + t + 512);
    }
    if (t < 4) {
        float s = scrs[0][t];
        for (int i = 1; i < 8; ++i) s += scrs[i][t];
        rzout[m0 + t] = __builtin_amdgcn_rcpf(s);
    }
}

// ---- context + final MLP ---------------------------------------------------
#define TMD 4
__global__ __launch_bounds__(1024) void k_ctx_mlp(const float* __restrict__ w_s,
                                                  const float* __restrict__ rz_s,
                                                  const float* __restrict__ w_e,
                                                  const float* __restrict__ rz_e,
                                                  const float* __restrict__ stmts,
                                                  const float* __restrict__ eres,
                                                  const float* __restrict__ attender,
                                                  const float* __restrict__ WT_lin,
                                                  const float* __restrict__ b_lin,
                                                  const float* __restrict__ W_coh,
                                                  const float* __restrict__ b_coh,
                                                  float* __restrict__ out) {
    __shared__ float wls[1024][TMD];
    __shared__ float part[8][TMD][H];
    __shared__ float feats[TMD][3 * H];
    __shared__ float redv[512];
    __shared__ float red8[8];
    int m0  = blockIdx.x * TMD;
    int tid = threadIdx.x;
    int h   = tid & (H - 1);
    int g   = tid >> 7;

    float rzs[TMD], rze[TMD];
    #pragma unroll
    for (int j = 0; j < TMD; ++j) { rzs[j] = rz_s[m0 + j]; rze[j] = rz_e[m0 + j]; }

    if (tid < TMD * H) feats[tid >> 7][tid & 127] = attender[(size_t)(m0 + (tid >> 7)) * H + (tid & 127)];

    float vws[TMD], vwe[TMD];
    #pragma unroll
    for (int j = 0; j < TMD; ++j)
        vws[j] = __builtin_nontemporal_load(w_s + (size_t)(m0 + j) * NS + tid);
    if (tid < 512) {
        #pragma unroll
        for (int j = 0; j < TMD; ++j)
            vwe[j] = __builtin_nontemporal_load(w_e + (size_t)(m0 + j) * NE + tid);
    }
    *(float4*)&wls[tid][0] = make_float4(vws[0], vws[1], vws[2], vws[3]);
    __syncthreads();

    // ---- ctx_s ----
    {
        float acc[TMD] = {0.f, 0.f, 0.f, 0.f};
        const float* Xb = stmts + (size_t)(g * 128) * H + h;
        #pragma unroll 8
        for (int nn = 0; nn < 128; ++nn) {
            float x = Xb[(size_t)nn * H];
            float4 w4 = *(const float4*)&wls[g * 128 + nn][0];
            acc[0] += w4.x * x; acc[1] += w4.y * x;
            acc[2] += w4.z * x; acc[3] += w4.w * x;
        }
        #pragma unroll
        for (int j = 0; j < TMD; ++j) part[g][j][h] = acc[j];
    }
    __syncthreads();
    if (tid < 512) {
        int j = tid >> 7, hh = tid & 127;
        float s = 0.f;
        #pragma unroll
        for (int gg = 0; gg < 8; ++gg) s += part[gg][j][hh];
        feats[j][H + hh] = s * rzs[j];
    }
    __syncthreads();

    // ---- ctx_e ----
    if (tid < 512) *(float4*)&wls[tid][0] = make_float4(vwe[0], vwe[1], vwe[2], vwe[3]);
    __syncthreads();
    {
        float acc[TMD] = {0.f, 0.f, 0.f, 0.f};
        const float* Xb = eres + (size_t)(g * 64) * H + h;
        #pragma unroll 8
        for (int nn = 0; nn < 64; ++nn) {
            float x = Xb[(size_t)nn * H];
            float4 w4 = *(const float4*)&wls[g * 64 + nn][0];
            acc[0] += w4.x * x; acc[1] += w4.y * x;
            acc[2] += w4.z * x; acc[3] += w4.w * x;
        }
        #pragma unroll
        for (int j = 0; j < TMD; ++j) part[g][j][h] = acc[j];
    }
    __syncthreads();
    if (tid < 512) {
        int j = tid >> 7, hh = tid & 127;
        float s = 0.f;
        #pragma unroll
        for (int gg = 0; gg < 8; ++gg) s += part[gg][j][hh];
        feats[j][2 * H + hh] = s * rze[j];
    }
    __syncthreads();

    // ---- final MLP + coherence ----
    {
        int a    = tid & 127;
        int jm   = (tid >> 7) & 3;
        int half = tid >> 9;
        float acc = half ? 0.f : b_lin[a];
        int k0 = half * 192;
        #pragma unroll 8
        for (int k = k0; k < k0 + 192; ++k)
            acc += feats[jm][k] * WT_lin[k * H + a];
        if (half) redv[tid & 511] = acc;
        __syncthreads();
        if (!half) {
            acc += redv[tid];
            float v = fast_tanh(acc) * W_coh[a];
            #pragma unroll
            for (int off = 32; off > 0; off >>= 1) v += __shfl_down(v, off, 64);
            if ((tid & 63) == 0) red8[tid >> 6] = v;
        }
        __syncthreads();
        if (tid < TMD) out[m0 + tid] = red8[2 * tid] + red8[2 * tid + 1] + b_coh[0];
    }
}

extern "C" void kernel_launch(void* const* d_in, const int* in_sizes, int n_in,
                              void* d_out, int out_size, void* d_ws, size_t ws_size,
                              hipStream_t stream) {
    const float* stmts    = (const float*)d_in[0];
    const float* eres     = (const float*)d_in[1];
    const float* attender = (const float*)d_in[2];
    const float* Wc_s     = (const float*)d_in[3];
    const float* bc_s     = (const float*)d_in[4];
    const float* ws_s     = (const float*)d_in[5];
    const float* Wc_e     = (const float*)d_in[7];
    const float* bc_e     = (const float*)d_in[8];
    const float* ws_e     = (const float*)d_in[9];
    const float* W_lin    = (const float*)d_in[11];
    const float* b_lin    = (const float*)d_in[12];
    const float* W_coh    = (const float*)d_in[13];
    const float* b_coh    = (const float*)d_in[14];
    float* out = (float*)d_out;

    float* ws    = (float*)d_ws;
    float* WT_s1 = ws;
    float* WT_s2 = WT_s1 + H * H;
    float* WT_e1 = WT_s2 + H * H;
    float* WT_e2 = WT_e1 + H * H;
    float* WT_li = WT_e2 + H * H;             // 384*128
    float* EAT_s = WT_li + 3 * H * H;         // [H][NS]
    float* EB_s  = EAT_s + NS * H;
    float* EAT_e = EB_s + M * H;              // [H][NE]
    float* EB_e  = EAT_e + NE * H;
    float* wbs   = EB_e + M * H;              // w_s [M][NS]
    float* wbe   = wbs + (size_t)M * NS;      // w_e [M][NE]
    float* rzs   = wbe + (size_t)M * NE;      // M
    float* rze   = rzs + M;                   // M

    k_tr<<<448, 256, 0, stream>>>(Wc_s, Wc_e, W_lin, WT_s1, WT_s2, WT_e1, WT_e2, WT_li);
    k_proj<<<608, 256, 0, stream>>>(stmts, eres, attender, WT_s1, WT_s2, WT_e1, WT_e2,
                                    bc_s, bc_e, EAT_s, EB_s, EAT_e, EB_e);
    k_score_w<<<512, 512, 0, stream>>>(EAT_s, EB_s, ws_s, EAT_e, EB_e, ws_e,
                                       wbs, rzs, wbe, rze);
    k_ctx_mlp<<<M / TMD, 1024, 0, stream>>>(wbs, rzs, wbe, rze, stmts, eres, attender,
                                            WT_li, b_lin, W_coh, b_coh, out);
}